// Round 4
// baseline (35.834 us; speedup 1.0000x reference)
//
#include <hip/hip_runtime.h>
#include <hip/hip_bf16.h>

// ARD kernel matrix: out[i][j] = exp(-0.5 * sum_d (x[i][d]-y[j][d])^2 / exp(lbw[d]))
// Quadratic expansion: weight rows by exp(-0.5*lbw), cast bf16, MFMA GEMM for the
// cross term, fused epilogue exp(-0.5*(x2+y2-2*cross)).
//
// Round 4 (= R3 + compile fix): 128x128 tile, full K=256 in LDS as two half-K
// buffers (split-K pipelining: stage(h1) flies under compute(h0)); 8 waves
// (512 thr, 2/SIMD); SWAPPED mfma operands so each lane's 4 acc regs are 4
// consecutive output floats -> dwordx4 nontemporal stores (8/thread vs 64
// scalar dwords). Fix: nontemporal store uses ext_vector float4, not HIP float4.

typedef __attribute__((ext_vector_type(8))) short bf16x8;   // 8 bf16 = 4 VGPRs
typedef __attribute__((ext_vector_type(4))) float f32x4;    // MFMA accumulator

#define NN 4096
#define MM 4096
#define DD 256

#define BM 128
#define BN 128
#define HK 128   // half of K

#define GLOAD16(gp, lp)                                                        \
    __builtin_amdgcn_global_load_lds(                                          \
        (const __attribute__((address_space(1))) void*)(gp),                   \
        (__attribute__((address_space(3))) void*)(lp), 16, 0, 0)

// ---------------------------------------------------------------------------
// prep: one wave per row (x rows then y rows). Scale by exp(-0.5*lbw), cast
// bf16, accumulate row norm from the ROUNDED values (keeps pdist >= 0).
// ---------------------------------------------------------------------------
__global__ __launch_bounds__(256) void ard_prep(
    const float* __restrict__ x, const float* __restrict__ y,
    const float* __restrict__ lbw,
    __hip_bfloat16* __restrict__ xw, __hip_bfloat16* __restrict__ yw,
    float* __restrict__ x2, float* __restrict__ y2)
{
    const int lane = threadIdx.x & 63;
    const int row  = blockIdx.x * 4 + (threadIdx.x >> 6);   // 0 .. N+M-1

    const float* src;
    __hip_bfloat16* dst;
    float* nrm;
    if (row < NN) {
        src = x + (size_t)row * DD;
        dst = xw + (size_t)row * DD;
        nrm = x2 + row;
    } else {
        const int r = row - NN;
        src = y + (size_t)r * DD;
        dst = yw + (size_t)r * DD;
        nrm = y2 + r;
    }

    const float4 v  = reinterpret_cast<const float4*>(src)[lane];
    const float4 lw = reinterpret_cast<const float4*>(lbw)[lane];

    float wv[4];
    wv[0] = v.x * __expf(-0.5f * lw.x);
    wv[1] = v.y * __expf(-0.5f * lw.y);
    wv[2] = v.z * __expf(-0.5f * lw.z);
    wv[3] = v.w * __expf(-0.5f * lw.w);

    __hip_bfloat16 h[4];
    float s = 0.0f;
#pragma unroll
    for (int j = 0; j < 4; ++j) {
        h[j] = __float2bfloat16(wv[j]);
        const float f = __bfloat162float(h[j]);
        s += f * f;
    }

    reinterpret_cast<uint2*>(dst)[lane] = *reinterpret_cast<uint2*>(h);

#pragma unroll
    for (int off = 32; off > 0; off >>= 1) s += __shfl_down(s, off);
    if (lane == 0) *nrm = s;
}

// ---------------------------------------------------------------------------
// GEMM + fused epilogue. 8 waves in 2x4; wave owns 64x32 output as 4x2 frags
// of mfma_f32_16x16x32_bf16 with OPERANDS SWAPPED (b_frag in slot A):
//   D col index (lane&15)        -> output ROW (xw row)
//   D row index ((lane>>4)*4+reg) -> output COL (yw row), 4 consecutive cols.
//
// LDS: per operand, two half-K buffers [128 rows][256 B]; logical byte-col c
// of row r lives at r*256 + (c ^ ((r&7)<<4)). global_load_lds writes linearly,
// so the swizzle is applied to the per-lane GLOBAL source address (rule #21).
// ---------------------------------------------------------------------------
__global__ __launch_bounds__(512) void ard_gemm(
    const __hip_bfloat16* __restrict__ A,   // xw [N][D]
    const __hip_bfloat16* __restrict__ B,   // yw [M][D]
    const float* __restrict__ x2, const float* __restrict__ y2,
    float* __restrict__ out)                // [N][M]
{
    __shared__ __align__(16) __hip_bfloat16 sA[2][BM * HK];  // 2 x 32 KB
    __shared__ __align__(16) __hip_bfloat16 sB[2][BN * HK];  // 2 x 32 KB

    const int tid  = threadIdx.x;
    const int lane = tid & 63;
    const int wid  = tid >> 6;     // 0..7
    const int wr   = wid >> 2;     // 0..1  (64-row band)
    const int wc   = wid & 3;      // 0..3  (32-col band)

    const int bi = blockIdx.y;
    const int bj = blockIdx.x;
    const size_t arow0 = (size_t)bi * BM;
    const size_t brow0 = (size_t)bj * BN;

    // staging: one GLOAD16 = 1 KB = 4 rows x 256 B. lane -> row r0+(lane>>4),
    // 16B slot lane&15. Wave w stages rows [w*16, w*16+16) of each buffer.
    const int crow = lane >> 4;          // 0..3 row within chunk
    const int slot = lane & 15;          // 16B slot within 256B row

    auto stage = [&](int h) {
        const int colb = h * 256;        // global byte-col base of this half
#pragma unroll
        for (int t = 0; t < 4; ++t) {
            const int r   = wid * 16 + t * 4;                 // wave-uniform
            const int row = r + crow;                         // per-lane
            const int lcb = colb + ((slot * 16) ^ ((row & 7) << 4));
            GLOAD16((const char*)(A + (arow0 + row) * DD) + lcb,
                    (char*)&sA[h][0] + r * 256);
            GLOAD16((const char*)(B + (brow0 + row) * DD) + lcb,
                    (char*)&sB[h][0] + r * 256);
        }
    };

    f32x4 acc[4][2] = {};
    const int frow = lane & 15;          // fragment row within 16
    const int fkb  = (lane >> 4) * 16;   // K byte sub-offset
    const int swz  = (frow & 7) << 4;    // row&7 == frow&7 (row bases %8==0)

    stage(0);
    __syncthreads();          // h0 staged (drains vmcnt)
    stage(1);                 // h1 loads fly under h0 compute

#pragma unroll
    for (int h = 0; h < 2; ++h) {
        if (h == 1) __syncthreads();     // h1 staged
#pragma unroll
        for (int kk = 0; kk < 4; ++kk) {
            const int kb = kk * 64 + fkb;
            bf16x8 a[4], b[2];
#pragma unroll
            for (int m = 0; m < 4; ++m) {
                const int row = wr * 64 + m * 16 + frow;
                a[m] = *reinterpret_cast<const bf16x8*>(
                    (const char*)&sA[h][0] + row * 256 + (kb ^ swz));
            }
#pragma unroll
            for (int n = 0; n < 2; ++n) {
                const int row = wc * 32 + n * 16 + frow;
                b[n] = *reinterpret_cast<const bf16x8*>(
                    (const char*)&sB[h][0] + row * 256 + (kb ^ swz));
            }
#pragma unroll
            for (int m = 0; m < 4; ++m)
#pragma unroll
                for (int n = 0; n < 2; ++n)
                    acc[m][n] = __builtin_amdgcn_mfma_f32_16x16x32_bf16(
                        b[n], a[m], acc[m][n], 0, 0, 0);   // SWAPPED
        }
    }

    // epilogue: out row = row0 + m*16 + (lane&15); cols = col0 + n*16 + rsub+j
    const int row0 = bi * BM + wr * 64;
    const int col0 = bj * BN + wc * 32;
    const int cl   = lane & 15;
    const int rsub = (lane >> 4) * 4;

#pragma unroll
    for (int m = 0; m < 4; ++m) {
        const int r = row0 + m * 16 + cl;
        const float xv = x2[r];
        float* orow = out + (size_t)r * MM;
#pragma unroll
        for (int n = 0; n < 2; ++n) {
            const int c = col0 + n * 16 + rsub;
            const float4 yv = *reinterpret_cast<const float4*>(y2 + c);
            f32x4 o;
            o.x = __expf(-0.5f * fmaxf(xv + yv.x - 2.0f * acc[m][n][0], 0.0f));
            o.y = __expf(-0.5f * fmaxf(xv + yv.y - 2.0f * acc[m][n][1], 0.0f));
            o.z = __expf(-0.5f * fmaxf(xv + yv.z - 2.0f * acc[m][n][2], 0.0f));
            o.w = __expf(-0.5f * fmaxf(xv + yv.w - 2.0f * acc[m][n][3], 0.0f));
            __builtin_nontemporal_store(o, reinterpret_cast<f32x4*>(orow + c));
        }
    }
}

extern "C" void kernel_launch(void* const* d_in, const int* in_sizes, int n_in,
                              void* d_out, int out_size, void* d_ws, size_t ws_size,
                              hipStream_t stream) {
    const float* x   = (const float*)d_in[0];
    const float* y   = (const float*)d_in[1];
    const float* lbw = (const float*)d_in[2];
    float* out = (float*)d_out;

    char* ws = (char*)d_ws;
    __hip_bfloat16* xw = (__hip_bfloat16*)ws;                             // 2 MB
    __hip_bfloat16* yw = (__hip_bfloat16*)(ws + (size_t)2 * 1024 * 1024); // 2 MB
    float* x2 = (float*)(ws + (size_t)4 * 1024 * 1024);                   // 16 KB
    float* y2 = (float*)(ws + (size_t)4 * 1024 * 1024 + 16384);           // 16 KB

    ard_prep<<<(NN + MM) / 4, 256, 0, stream>>>(x, y, lbw, xw, yw, x2, y2);

    dim3 grid(MM / BN, NN / BM);
    ard_gemm<<<grid, 512, 0, stream>>>(xw, yw, x2, y2, out);
}